// Round 14
// baseline (140.148 us; speedup 1.0000x reference)
//
#include <hip/hip_runtime.h>

// ---------------------------------------------------------------------------
// Fused causal MHA:  out = attn(x@Wqkv+b) @ Wproj + bproj
// B=2, L=2048, D=1024, H=16, DH=64
// Device buffers may be f32 or bf16 (runtime-detected); bf16 MFMA internally.
// Softmax in exp2 space (Q pre-scaled by 0.125*log2e in the QKV epilogue).
// ---------------------------------------------------------------------------

typedef __bf16 bf16x8 __attribute__((ext_vector_type(8)));
typedef float  f32x4  __attribute__((ext_vector_type(4)));
typedef unsigned short bhalf;
typedef unsigned int   uint32;

#define B_  2
#define L_  2048
#define D_  1024
#define H_  16
#define DH_ 64

#define GPTR(p) ((const __attribute__((address_space(1))) void*)(p))
#define SPTR(p) ((__attribute__((address_space(3))) void*)(p))

static __device__ __forceinline__ float bf2f(bhalf u) {
    union { uint32 u; float f; } x; x.u = ((uint32)u) << 16; return x.f;
}
static __device__ __forceinline__ bhalf f2bf(float f) {
    union { float f; uint32 u; } x; x.f = f;
    uint32 r = x.u + 0x7FFFu + ((x.u >> 16) & 1u);   // RNE
    return (bhalf)(r >> 16);
}

// ---------------------------------------------------------------------------
__global__ void detect_dtype(const uint32* __restrict__ xw, int* __restrict__ flag) {
    int t = threadIdx.x;                     // 64 threads
    uint32 w = xw[t];
    uint32 e = (w >> 7) & 0xFFu;             // exponent of low-half bf16
    int g = (e < 0x6Fu || e > 0x84u) ? 1 : 0;
#pragma unroll
    for (int off = 32; off; off >>= 1) g += __shfl_xor(g, off);
    if (t == 0) *flag = (g > 16) ? 0 : 1;
}

// ---------------------------------------------------------------------------
__global__ void conv_bf16(const void* __restrict__ in, bhalf* __restrict__ out,
                          int n4, const int* __restrict__ flag) {
    const bool isb = (*flag != 0);
    for (int i = blockIdx.x * blockDim.x + threadIdx.x; i < n4;
         i += gridDim.x * blockDim.x) {
        if (isb) {
            ((uint2*)out)[i] = ((const uint2*)in)[i];
        } else {
            float4 v = ((const float4*)in)[i];
            uint2 o;
            o.x = (uint32)f2bf(v.x) | ((uint32)f2bf(v.y) << 16);
            o.y = (uint32)f2bf(v.z) | ((uint32)f2bf(v.w) << 16);
            ((uint2*)out)[i] = o;
        }
    }
}

// ---------------------------------------------------------------------------
__global__ void tr_conv(const void* __restrict__ in, bhalf* __restrict__ out,
                        int R, int C, const int* __restrict__ flag) {
    __shared__ bhalf t[32][33];
    const bool isb = (*flag != 0);
    int bx = blockIdx.x, by = blockIdx.y;
    int tx = threadIdx.x, ty = threadIdx.y;   // (32, 8)
#pragma unroll
    for (int i = 0; i < 32; i += 8) {
        size_t idx = (size_t)(by * 32 + ty + i) * C + bx * 32 + tx;
        t[ty + i][tx] = isb ? ((const bhalf*)in)[idx]
                            : f2bf(((const float*)in)[idx]);
    }
    __syncthreads();
#pragma unroll
    for (int i = 0; i < 32; i += 8)
        out[(size_t)(bx * 32 + ty + i) * R + by * 32 + tx] = t[tx][ty + i];
}

// ---------------------------------------------------------------------------
// QKV GEMM, 128x64 tile (BM=128, BN=64, BK=32), 256 threads = 4 waves each
// 64x32. Grid 48x32 = 1536 blocks = 6/CU (vs 3/CU at 128x128 -- the 128x128
// variant was GRID-limited: LDS cap 5, VGPR cap 6w/SIMD, but only 3 blocks).
// Same proven 2-buffer prefetch structure + chunk permutation.
// Epilogue scatters Q (pre-scaled by 0.125*log2e), K -> [B,H,L,DH],
// V -> Vt [B,H,DH,L].
// ---------------------------------------------------------------------------
#define QSTAGE(BUF, KK) do {                                                  \
    int kko = (KK);                                                           \
    _Pragma("unroll")                                                         \
    for (int r = 0; r < 2; r++) {       /* A tile 128x32 */                   \
        int c = r * 256 + tid;                                                \
        int row = c >> 2, p = c & 3;                                          \
        int gch = (p - row - (row >> 2)) & 3;                                 \
        __builtin_amdgcn_global_load_lds(                                     \
            GPTR(a0 + (size_t)row * K + kko + gch * 8),                       \
            SPTR(As[BUF] + (r * 256 + w * 64) * 8), 16, 0, 0);                \
    }                                                                         \
    {                                   /* B tile 64x32 */                    \
        int c = tid;                                                          \
        int row = c >> 2, p = c & 3;                                          \
        int gch = (p - row - (row >> 2)) & 3;                                 \
        __builtin_amdgcn_global_load_lds(                                     \
            GPTR(b0 + (size_t)row * K + kko + gch * 8),                       \
            SPTR(Bs[BUF] + (w * 64) * 8), 16, 0, 0);                          \
    }                                                                         \
} while (0)

__global__ __launch_bounds__(256, 4) void gemm_qkv64(
        const bhalf* __restrict__ A, const bhalf* __restrict__ Bt,
        const void* __restrict__ bias,
        bhalf* __restrict__ Qb, bhalf* __restrict__ Kb, bhalf* __restrict__ Vtb,
        int K, const int* __restrict__ flag) {
    __shared__ bhalf As[2][128 * 32];   // 2 x 8 KB
    __shared__ bhalf Bs[2][64 * 32];    // 2 x 4 KB   (24 KB total -> 6/CU)
    const bool isb = (*flag != 0);
    const int tid = threadIdx.x;
    const int w = tid >> 6, lane = tid & 63;
    const int g = lane >> 4, cl = lane & 15;
    const int m0 = blockIdx.y * 128, n0 = blockIdx.x * 64;
    const int wr = (w >> 1) * 64, wc = (w & 1) * 32;

    f32x4 acc[4][2] = {};

    const bhalf* a0 = A  + (size_t)m0 * K;
    const bhalf* b0 = Bt + (size_t)n0 * K;

    QSTAGE(0, 0);
    __syncthreads();

    const int nk = K >> 5;
    for (int t = 0; t < nk; ++t) {
        int cur = t & 1;
        if (t + 1 < nk) QSTAGE(cur ^ 1, (t + 1) << 5);   // prefetch next tile

        bf16x8 af[4], bf2[2];
#pragma unroll
        for (int i = 0; i < 4; i++) {
            int ra = wr + i * 16 + cl;
            af[i] = *(const bf16x8*)(As[cur] + ra * 32 +
                                     (((g + ra + (ra >> 2)) & 3) * 8));
        }
#pragma unroll
        for (int n = 0; n < 2; n++) {
            int rb = wc + n * 16 + cl;
            bf2[n] = *(const bf16x8*)(Bs[cur] + rb * 32 +
                                      (((g + rb + (rb >> 2)) & 3) * 8));
        }
        __builtin_amdgcn_s_setprio(1);
#pragma unroll
        for (int i = 0; i < 4; i++)
#pragma unroll
            for (int n = 0; n < 2; n++)
                acc[i][n] = __builtin_amdgcn_mfma_f32_16x16x32_bf16(
                    af[i], bf2[n], acc[i][n], 0, 0, 0);
        __builtin_amdgcn_s_setprio(0);

        __syncthreads();   // next buffer staged; cur free to overwrite
    }

    // epilogue: C/D layout col = lane&15, row = (lane>>4)*4 + reg; QKV scatter
#pragma unroll
    for (int i = 0; i < 4; i++) {
#pragma unroll
        for (int n = 0; n < 2; n++) {
            int nn = n0 + wc + n * 16 + cl;
            float bv = isb ? bf2f(((const bhalf*)bias)[nn])
                           : ((const float*)bias)[nn];
#pragma unroll
            for (int r = 0; r < 4; r++) {
                int mm = m0 + wr + i * 16 + g * 4 + r;
                float v = acc[i][n][r] + bv;
                int b = mm >> 11, l = mm & 2047;
                int three = nn >> 10, rem = nn & 1023;
                int h = rem >> 6, dh = rem & 63;
                size_t bh = (size_t)(b * 16 + h);
                if (three == 0) {
                    // fold SCALE * log2(e) into Q (softmax in exp2 space)
                    Qb[(bh * 2048 + l) * 64 + dh] = f2bf(v * 0.18033688f);
                } else if (three == 1) {
                    Kb [(bh * 2048 + l) * 64 + dh] = f2bf(v);
                } else {
                    Vtb[(bh * 64 + dh) * 2048 + l] = f2bf(v);
                }
            }
        }
    }
}

// ---------------------------------------------------------------------------
// GEMM  C[M][N] = A[M][K] @ Bt[N][K]^T + bias[N]  (output projection; control
// kernel, unchanged round-6 structure). 128x128, BK=32, 4 waves, dbuf LDS.
// ---------------------------------------------------------------------------
#define GSTAGE(BUF, KK) do {                                                  \
    int kko = (KK);                                                           \
    _Pragma("unroll")                                                         \
    for (int r = 0; r < 2; r++) {                                             \
        int c = r * 256 + tid;                                                \
        int row = c >> 2, p = c & 3;                                          \
        int gch = (p - row - (row >> 2)) & 3;                                 \
        __builtin_amdgcn_global_load_lds(                                     \
            GPTR(a0 + (size_t)row * K + kko + gch * 8),                       \
            SPTR(As[BUF] + (r * 256 + w * 64) * 8), 16, 0, 0);                \
        __builtin_amdgcn_global_load_lds(                                     \
            GPTR(b0 + (size_t)row * K + kko + gch * 8),                       \
            SPTR(Bs[BUF] + (r * 256 + w * 64) * 8), 16, 0, 0);                \
    }                                                                         \
} while (0)

__global__ __launch_bounds__(256) void gemm_proj(
        const bhalf* __restrict__ A, const bhalf* __restrict__ Bt,
        const void* __restrict__ bias, void* __restrict__ C0,
        int M, int N, int K, const int* __restrict__ flag) {
    __shared__ bhalf As[2][128 * 32];
    __shared__ bhalf Bs[2][128 * 32];
    const bool isb = (*flag != 0);
    const int tid  = threadIdx.x;
    const int w    = tid >> 6, lane = tid & 63;
    const int g    = lane >> 4, cl = lane & 15;
    const int m0   = blockIdx.y * 128, n0 = blockIdx.x * 128;
    const int wr   = (w >> 1) * 64, wc = (w & 1) * 64;

    f32x4 acc[4][4] = {};

    const bhalf* a0 = A  + (size_t)m0 * K;
    const bhalf* b0 = Bt + (size_t)n0 * K;

    GSTAGE(0, 0);
    __syncthreads();

    const int nk = K >> 5;
    for (int t = 0; t < nk; ++t) {
        int cur = t & 1;
        if (t + 1 < nk) GSTAGE(cur ^ 1, (t + 1) << 5);

        bf16x8 af[4], bf4[4];
#pragma unroll
        for (int i = 0; i < 4; i++) {
            int ra = wr + i * 16 + cl;
            af[i]  = *(const bf16x8*)(As[cur] + ra * 32 +
                                      (((g + ra + (ra >> 2)) & 3) * 8));
            int rb = wc + i * 16 + cl;
            bf4[i] = *(const bf16x8*)(Bs[cur] + rb * 32 +
                                      (((g + rb + (rb >> 2)) & 3) * 8));
        }
        __builtin_amdgcn_s_setprio(1);
#pragma unroll
        for (int i = 0; i < 4; i++)
#pragma unroll
            for (int j = 0; j < 4; j++)
                acc[i][j] = __builtin_amdgcn_mfma_f32_16x16x32_bf16(
                    af[i], bf4[j], acc[i][j], 0, 0, 0);
        __builtin_amdgcn_s_setprio(0);

        __syncthreads();
    }

#pragma unroll
    for (int i = 0; i < 4; i++) {
#pragma unroll
        for (int j = 0; j < 4; j++) {
            int nn = n0 + wc + j * 16 + cl;
            float bv = isb ? bf2f(((const bhalf*)bias)[nn])
                           : ((const float*)bias)[nn];
#pragma unroll
            for (int r = 0; r < 4; r++) {
                int mm = m0 + wr + i * 16 + g * 4 + r;
                float v = acc[i][j][r] + bv;
                if (isb) ((bhalf*)C0)[(size_t)mm * N + nn] = f2bf(v);
                else     ((float*)C0)[(size_t)mm * N + nn] = v;
            }
        }
    }
}

// ---------------------------------------------------------------------------
// Causal flash attention (unchanged from round 13): swapped-QK^T, in-register
// exp2 softmax, KVBLK=64, 1024 blocks (one 64-row q-tile each), dbuf LDS.
// ---------------------------------------------------------------------------
#define STAGE(BUF, KT) do {                                                   \
    int ktv = (KT);                                                           \
    _Pragma("unroll")                                                         \
    for (int r = 0; r < 2; r++) {                                             \
        int c = r * 256 + tid;                                                \
        int row = c >> 3, p = c & 7;                                          \
        int fsw = (row & 3) | (((row >> 3) & 1) << 2);                        \
        __builtin_amdgcn_global_load_lds(                                     \
            GPTR(Kp + (size_t)(ktv * 64 + row) * 64 + (p ^ fsw) * 8),         \
            SPTR(Ks[BUF] + (r * 256 + w * 64) * 8), 16, 0, 0);                \
    }                                                                         \
    _Pragma("unroll")                                                         \
    for (int r = 0; r < 2; r++) {                                             \
        int c = r * 256 + tid;                                                \
        int row = c >> 3, p = c & 7;                                          \
        __builtin_amdgcn_global_load_lds(                                     \
            GPTR(Vt + (size_t)row * L_ + ktv * 64 + (p ^ (row & 7)) * 8),     \
            SPTR(Vs[BUF] + (r * 256 + w * 64) * 8), 16, 0, 0);                \
    }                                                                         \
} while (0)

#define ATTN_TILE(BUF, KT, QF, QLANE, MVAR, LVAR, OACC, MASK) do {            \
    f32x4 p8[4] = {};                                                         \
    _Pragma("unroll")                                                         \
    for (int s = 0; s < 2; s++) {                                             \
        bf16x8 kf[4];                                                         \
        _Pragma("unroll")                                                     \
        for (int j = 0; j < 4; j++) {                                         \
            int row = (j >> 1) * 32 + (cl >> 2) * 8 + (j & 1) * 4 + (cl & 3); \
            int fsw = (row & 3) | (((row >> 3) & 1) << 2);                    \
            int ch = s * 4 + g;                                               \
            kf[j] = *(const bf16x8*)(Ks[BUF] + row * 64 + ((ch ^ fsw) * 8));  \
        }                                                                     \
        __builtin_amdgcn_s_setprio(1);                                        \
        _Pragma("unroll")                                                     \
        for (int j = 0; j < 4; j++)                                           \
            p8[j] = __builtin_amdgcn_mfma_f32_16x16x32_bf16(                  \
                kf[j], QF[s], p8[j], 0, 0, 0);                                \
        __builtin_amdgcn_s_setprio(0);                                        \
    }                                                                         \
    float mx0 = -__builtin_inff(), mx1 = -__builtin_inff();                   \
    float mx2 = -__builtin_inff(), mx3 = -__builtin_inff();                   \
    _Pragma("unroll")                                                         \
    for (int j = 0; j < 4; j++) {                                             \
        float v0 = p8[j][0], v1 = p8[j][1], v2 = p8[j][2], v3 = p8[j][3];     \
        if (MASK) {                                                           \
            int ka = (KT) * 64 + (j >> 1) * 32 + g * 8 + ((j & 1) << 2);      \
            v0 = (ka + 0 > (QLANE)) ? -__builtin_inff() : v0;                 \
            v1 = (ka + 1 > (QLANE)) ? -__builtin_inff() : v1;                 \
            v2 = (ka + 2 > (QLANE)) ? -__builtin_inff() : v2;                 \
            v3 = (ka + 3 > (QLANE)) ? -__builtin_inff() : v3;                 \
            p8[j][0] = v0; p8[j][1] = v1; p8[j][2] = v2; p8[j][3] = v3;       \
        }                                                                     \
        mx0 = fmaxf(mx0, v0); mx1 = fmaxf(mx1, v1);                           \
        mx2 = fmaxf(mx2, v2); mx3 = fmaxf(mx3, v3);                           \
    }                                                                         \
    float mx = fmaxf(fmaxf(mx0, mx1), fmaxf(mx2, mx3));                       \
    mx = fmaxf(mx, __shfl_xor(mx, 16));                                       \
    mx = fmaxf(mx, __shfl_xor(mx, 32));                                       \
    if (!__all(mx - MVAR <= 8.f)) {      /* defer-max */                      \
        float mnew = fmaxf(MVAR, mx);                                         \
        float alpha = __builtin_amdgcn_exp2f(MVAR - mnew);                    \
        MVAR = mnew;                                                          \
        LVAR *= alpha;                                                        \
        _Pragma("unroll")                                                     \
        for (int r = 0; r < 4; r++) {                                         \
            float ar = __shfl(alpha, g * 4 + r);                              \
            _Pragma("unroll")                                                 \
            for (int dj = 0; dj < 4; dj++) OACC[dj][r] *= ar;                 \
        }                                                                     \
    }                                                                         \
    float s0 = 0.f, s1 = 0.f, s2 = 0.f, s3 = 0.f;                             \
    _Pragma("unroll")                                                         \
    for (int j = 0; j < 4; j++) {                                             \
        float e0 = __builtin_amdgcn_exp2f(p8[j][0] - MVAR);                   \
        float e1 = __builtin_amdgcn_exp2f(p8[j][1] - MVAR);                   \
        float e2 = __builtin_amdgcn_exp2f(p8[j][2] - MVAR);                   \
        float e3 = __builtin_amdgcn_exp2f(p8[j][3] - MVAR);                   \
        p8[j][0] = e0; p8[j][1] = e1; p8[j][2] = e2; p8[j][3] = e3;           \
        s0 += e0; s1 += e1; s2 += e2; s3 += e3;                               \
    }                                                                         \
    float ls = (s0 + s1) + (s2 + s3);                                         \
    ls += __shfl_xor(ls, 16);                                                 \
    ls += __shfl_xor(ls, 32);                                                 \
    LVAR += ls;                                                               \
    _Pragma("unroll")                                                         \
    for (int ks = 0; ks < 2; ks++) {                                          \
        bf16x8 pf;                                                            \
        _Pragma("unroll")                                                     \
        for (int e = 0; e < 8; e++)                                           \
            pf[e] = (__bf16)p8[2 * ks + (e >> 2)][e & 3];                     \
        bf16x8 vf[4];                                                         \
        _Pragma("unroll")                                                     \
        for (int dj = 0; dj < 4; dj++) {                                      \
            int vrow = dj * 16 + cl;                                          \
            int ch = ks * 4 + g;                                              \
            vf[dj] = *(const bf16x8*)(Vs[BUF] + vrow * 64 + ((ch ^ (vrow & 7)) * 8)); \
        }                                                                     \
        __builtin_amdgcn_s_setprio(1);                                        \
        _Pragma("unroll")                                                     \
        for (int dj = 0; dj < 4; dj++)                                        \
            OACC[dj] = __builtin_amdgcn_mfma_f32_16x16x32_bf16(               \
                pf, vf[dj], OACC[dj], 0, 0, 0);                               \
        __builtin_amdgcn_s_setprio(0);                                        \
    }                                                                         \
} while (0)

__global__ __launch_bounds__(256, 4) void attn_fwd(
        const bhalf* __restrict__ Qb, const bhalf* __restrict__ Kb,
        const bhalf* __restrict__ Vtb, bhalf* __restrict__ Ob) {
    __shared__ bhalf Ks[2][64 * 64];   // [buf][krow][d]  swz (row&3)|(((row>>3)&1)<<2)
    __shared__ bhalf Vs[2][64 * 64];   // [buf][d][kcol]  swz row&7

    const int bid  = blockIdx.x;              // 0..1023
    const int xcd  = bid & 7, slot = bid >> 3;
    const int v    = slot & 31, grp = slot >> 5;     // v: 0..31, grp: 0..3
    const int qb   = (grp & 1) ? v : (31 - v);       // balanced across grp
    const int bh   = xcd + 8 * grp;                  // same-bh on one XCD

    const int tid = threadIdx.x;
    const int w = tid >> 6, lane = tid & 63;
    const int g = lane >> 4, cl = lane & 15;

    const bhalf* Q  = Qb  + (size_t)bh * L_ * DH_;
    const bhalf* Kp = Kb  + (size_t)bh * L_ * DH_;
    const bhalf* Vt = Vtb + (size_t)bh * DH_ * L_;

    const int q0 = qb * 64 + w * 16;          // wave's first q-row
    const int ql = q0 + cl;                   // this lane's softmax row

    bf16x8 qf[2];
#pragma unroll
    for (int s = 0; s < 2; s++)
        qf[s] = *(const bf16x8*)(Q + (size_t)(q0 + cl) * 64 + s * 32 + g * 8);

    f32x4 oacc[4] = {};
    float m = -__builtin_inff(), l = 0.f;

    const int nkt = qb + 1;                   // 64-wide k-tiles

    STAGE(0, 0);
    __syncthreads();

    for (int kt = 0; kt < nkt; ++kt) {
        int cur = kt & 1;
        if (kt + 1 < nkt) STAGE(cur ^ 1, kt + 1);   // prefetch next tile
        ATTN_TILE(cur, kt, qf, ql, m, l, oacc, (kt == nkt - 1));
        __syncthreads();   // next buffer staged; current free to overwrite
    }

    // epilogue: divide by denom (+1e-6 per reference), write O [B,L,D]
    const int b = bh >> 4, h = bh & 15;
#pragma unroll
    for (int r = 0; r < 4; r++) {
        float lr  = __shfl(l, g * 4 + r);
        float inv = 1.f / (lr + 1e-6f);
        int qrow = q0 + g * 4 + r;
#pragma unroll
        for (int dj = 0; dj < 4; dj++)
            Ob[((size_t)b * L_ + qrow) * D_ + h * 64 + dj * 16 + cl] =
                f2bf(oacc[dj][r] * inv);
    }
}

// ---------------------------------------------------------------------------
extern "C" void kernel_launch(void* const* d_in, const int* in_sizes, int n_in,
                              void* d_out, int out_size, void* d_ws, size_t ws_size,
                              hipStream_t stream) {
    const void* x     = d_in[0];   // [B,L,D]     f32 or bf16
    const void* Wqkv  = d_in[1];   // [D, 3D]
    const void* bqkv  = d_in[2];   // [3D]
    const void* Wproj = d_in[3];   // [D, D]
    const void* bproj = d_in[4];   // [D]

    char* ws = (char*)d_ws;
    const size_t SZ_FLG = 256;
    const size_t SZ_WQT = (size_t)3 * D_ * D_ * 2;        //  6 MB
    const size_t SZ_WPT = (size_t)D_ * D_ * 2;            //  2 MB
    const size_t SZ_X   = (size_t)B_ * L_ * D_ * 2;       //  8 MB
    const size_t SZ_BUF = (size_t)B_ * H_ * L_ * DH_ * 2; //  8 MB each

    int*   flag = (int*)ws;
    bhalf* Wq_t = (bhalf*)(ws + SZ_FLG);
    bhalf* Wp_t = (bhalf*)(ws + SZ_FLG + SZ_WQT);
    bhalf* Xb   = (bhalf*)(ws + SZ_FLG + SZ_WQT + SZ_WPT);
    bhalf* Qbuf = (bhalf*)(ws + SZ_FLG + SZ_WQT + SZ_WPT + SZ_X);
    bhalf* Kbuf = (bhalf*)(ws + SZ_FLG + SZ_WQT + SZ_WPT + SZ_X + SZ_BUF);
    bhalf* Vtbf = (bhalf*)(ws + SZ_FLG + SZ_WQT + SZ_WPT + SZ_X + 2 * SZ_BUF);
    bhalf* Obuf = (bhalf*)(ws + SZ_FLG + SZ_WQT + SZ_WPT + SZ_X + 3 * SZ_BUF);

    const int M = B_ * L_;   // 4096

    // 0. runtime dtype detection
    detect_dtype<<<1, 64, 0, stream>>>((const uint32*)x, flag);

    // 1. canonicalize inputs to bf16 workspace
    conv_bf16<<<2048, 256, 0, stream>>>(x, Xb, (B_ * L_ * D_) / 4, flag);
    tr_conv<<<dim3(3 * D_ / 32, D_ / 32), dim3(32, 8), 0, stream>>>(
        Wqkv, Wq_t, D_, 3 * D_, flag);
    tr_conv<<<dim3(D_ / 32, D_ / 32), dim3(32, 8), 0, stream>>>(
        Wproj, Wp_t, D_, D_, flag);

    // 2. QKV projection, 128x64 tile -> 1536 blocks = 6/CU
    gemm_qkv64<<<dim3(3 * D_ / 64, M / 128), 256, 0, stream>>>(
        Xb, Wq_t, bqkv, Qbuf, Kbuf, Vtbf, D_, flag);

    // 3. causal flash attention -> Obuf [B,L,D] bf16
    attn_fwd<<<dim3(1024), 256, 0, stream>>>(Qbuf, Kbuf, Vtbf, Obuf);

    // 4. output projection -> d_out
    gemm_proj<<<dim3(D_ / 128, M / 128), 256, 0, stream>>>(
        Obuf, Wp_t, bproj, d_out, M, D_, D_, flag);
}

// Round 15
// 118.571 us; speedup vs baseline: 1.1820x; 1.1820x over previous
//
#include <hip/hip_runtime.h>

// ---------------------------------------------------------------------------
// Fused causal MHA:  out = attn(x@Wqkv+b) @ Wproj + bproj
// B=2, L=2048, D=1024, H=16, DH=64
// Buffers are f32 (proven: MODE-0 f32 output writes pass validation).
// bf16 MFMA internally; GEMM1 stages A directly from f32 x (no conv kernel).
// Softmax in exp2 space (Q pre-scaled by 0.125*log2e in the QKV epilogue).
// ---------------------------------------------------------------------------

typedef __bf16 bf16x8 __attribute__((ext_vector_type(8)));
typedef float  f32x4  __attribute__((ext_vector_type(4)));
typedef unsigned short bhalf;
typedef unsigned int   uint32;

#define B_  2
#define L_  2048
#define D_  1024
#define H_  16
#define DH_ 64

#define GPTR(p) ((const __attribute__((address_space(1))) void*)(p))
#define SPTR(p) ((__attribute__((address_space(3))) void*)(p))

static __device__ __forceinline__ float bf2f(bhalf u) {
    union { uint32 u; float f; } x; x.u = ((uint32)u) << 16; return x.f;
}
static __device__ __forceinline__ bhalf f2bf(float f) {
    union { float f; uint32 u; } x; x.f = f;
    uint32 r = x.u + 0x7FFFu + ((x.u >> 16) & 1u);   // RNE
    return (bhalf)(r >> 16);
}

// ---------------------------------------------------------------------------
// transpose + convert: in [R][C] f32 -> out [C][R] bf16
// ---------------------------------------------------------------------------
__global__ void tr_conv(const float* __restrict__ in, bhalf* __restrict__ out,
                        int R, int C) {
    __shared__ bhalf t[32][33];
    int bx = blockIdx.x, by = blockIdx.y;
    int tx = threadIdx.x, ty = threadIdx.y;   // (32, 8)
#pragma unroll
    for (int i = 0; i < 32; i += 8)
        t[ty + i][tx] = f2bf(in[(size_t)(by * 32 + ty + i) * C + bx * 32 + tx]);
    __syncthreads();
#pragma unroll
    for (int i = 0; i < 32; i += 8)
        out[(size_t)(bx * 32 + ty + i) * R + by * 32 + tx] = t[tx][ty + i];
}

// ---------------------------------------------------------------------------
// GEMM  C[M][N] = A[M][K] @ Bt[N][K]^T + bias[N]
// 128x128 tile, BK=32, 256 threads = 4 waves each 64x64 (round-6 proven
// 2-phase dbuf structure: prefetch-next-before-compute, 1 barrier/k-step).
// MODE 1 (QKV): A is **f32** (raw x) staged into f32 LDS, converted to bf16
//   at fragment-load (RNE) -- eliminates the standalone conv kernel.
//   Epilogue scatters Q (pre-scaled by 0.125*log2e), K -> [B,H,L,DH],
//   V -> Vt [B,H,DH,L].
// MODE 0 (proj): A is bf16 (attn output), C written f32.
// bf16 LDS: 4-chunk row permute (c+row+(row>>2))&3.  f32 LDS: 8-chunk
// permute (c+row)&7 (row stride 128B = full bank cycle, so row term must
// reach all 8 chunk slots; 64-lane b128 reads sit at the 8-cycle LDS floor).
// ---------------------------------------------------------------------------
template <int MODE>
__global__ __launch_bounds__(256) void gemm_bt(
        const void* __restrict__ A, const bhalf* __restrict__ Bt,
        const float* __restrict__ bias,
        float* __restrict__ C0, bhalf* __restrict__ Qb,
        bhalf* __restrict__ Kb, bhalf* __restrict__ Vtb,
        int M, int N, int K) {
    __shared__ float AsF[(MODE == 1) ? 2 * 128 * 32 : 2];   // 2 x 16 KB (MODE 1)
    __shared__ bhalf AsH[(MODE == 0) ? 2 * 128 * 32 : 2];   // 2 x 8 KB  (MODE 0)
    __shared__ bhalf Bs[2 * 128 * 32];                      // 2 x 8 KB
    const int tid  = threadIdx.x;
    const int w    = tid >> 6, lane = tid & 63;
    const int g    = lane >> 4, cl = lane & 15;
    const int m0   = blockIdx.y * 128, n0 = blockIdx.x * 128;
    const int wr   = (w >> 1) * 64, wc = (w & 1) * 64;

    f32x4 acc[4][4] = {};

    const float* a0f = (const float*)A + (size_t)m0 * K;
    const bhalf* a0h = (const bhalf*)A + (size_t)m0 * K;
    const bhalf* b0  = Bt + (size_t)n0 * K;

    auto stage = [&](int buf, int kk) {
        if (MODE == 1) {
            // A tile 128x32 f32 = 16 KB: 4 loads, 8 chunks (16B=4 f32) per row
#pragma unroll
            for (int r = 0; r < 4; r++) {
                int c = r * 256 + tid;
                int row = c >> 3, p = c & 7;
                int gch = (p - row) & 7;
                __builtin_amdgcn_global_load_lds(
                    GPTR(a0f + (size_t)row * K + kk + gch * 4),
                    SPTR(AsF + buf * 4096 + (r * 256 + w * 64) * 4), 16, 0, 0);
            }
        } else {
            // A tile 128x32 bf16 = 8 KB: 2 loads, 4 chunks (16B=8 bf16) per row
#pragma unroll
            for (int r = 0; r < 2; r++) {
                int c = r * 256 + tid;
                int row = c >> 2, p = c & 3;
                int gch = (p - row - (row >> 2)) & 3;
                __builtin_amdgcn_global_load_lds(
                    GPTR(a0h + (size_t)row * K + kk + gch * 8),
                    SPTR(AsH + buf * 4096 + (r * 256 + w * 64) * 8), 16, 0, 0);
            }
        }
        // B tile 128x32 bf16 = 8 KB
#pragma unroll
        for (int r = 0; r < 2; r++) {
            int c = r * 256 + tid;
            int row = c >> 2, p = c & 3;
            int gch = (p - row - (row >> 2)) & 3;
            __builtin_amdgcn_global_load_lds(
                GPTR(b0 + (size_t)row * K + kk + gch * 8),
                SPTR(Bs + buf * 4096 + (r * 256 + w * 64) * 8), 16, 0, 0);
        }
    };

    stage(0, 0);
    __syncthreads();

    const int nk = K >> 5;
    for (int t = 0; t < nk; ++t) {
        int cur = t & 1;
        if (t + 1 < nk) stage(cur ^ 1, (t + 1) << 5);   // prefetch next tile

        bf16x8 af[4], bf4[4];
#pragma unroll
        for (int i = 0; i < 4; i++) {
            int ra = wr + i * 16 + cl;
            if (MODE == 1) {
                const float* base = AsF + cur * 4096 + ra * 32;
                f32x4 x0 = *(const f32x4*)(base + (((2 * g + ra) & 7) * 4));
                f32x4 x1 = *(const f32x4*)(base + (((2 * g + 1 + ra) & 7) * 4));
#pragma unroll
                for (int e = 0; e < 4; e++) {
                    af[i][e]     = (__bf16)x0[e];
                    af[i][4 + e] = (__bf16)x1[e];
                }
            } else {
                af[i] = *(const bf16x8*)(AsH + cur * 4096 + ra * 32 +
                                         (((g + ra + (ra >> 2)) & 3) * 8));
            }
            int rb = wc + i * 16 + cl;
            bf4[i] = *(const bf16x8*)(Bs + cur * 4096 + rb * 32 +
                                      (((g + rb + (rb >> 2)) & 3) * 8));
        }
        __builtin_amdgcn_s_setprio(1);
#pragma unroll
        for (int i = 0; i < 4; i++)
#pragma unroll
            for (int j = 0; j < 4; j++)
                acc[i][j] = __builtin_amdgcn_mfma_f32_16x16x32_bf16(
                    af[i], bf4[j], acc[i][j], 0, 0, 0);
        __builtin_amdgcn_s_setprio(0);

        __syncthreads();   // next buffer staged; cur free to overwrite
    }

    // epilogue: C/D layout col = lane&15, row = (lane>>4)*4 + reg
#pragma unroll
    for (int i = 0; i < 4; i++) {
#pragma unroll
        for (int j = 0; j < 4; j++) {
            int nn = n0 + wc + j * 16 + cl;
            float bv = bias[nn];
#pragma unroll
            for (int r = 0; r < 4; r++) {
                int mm = m0 + wr + i * 16 + g * 4 + r;
                float v = acc[i][j][r] + bv;
                if (MODE == 0) {
                    C0[(size_t)mm * N + nn] = v;
                } else {
                    int b = mm >> 11, l = mm & 2047;
                    int three = nn >> 10, rem = nn & 1023;
                    int h = rem >> 6, dh = rem & 63;
                    size_t bh = (size_t)(b * 16 + h);
                    if (three == 0) {
                        // fold SCALE * log2(e) into Q (softmax in exp2 space)
                        Qb[(bh * 2048 + l) * 64 + dh] = f2bf(v * 0.18033688f);
                    } else if (three == 1) {
                        Kb [(bh * 2048 + l) * 64 + dh] = f2bf(v);
                    } else {
                        Vtb[(bh * 64 + dh) * 2048 + l] = f2bf(v);
                    }
                }
            }
        }
    }
}

// ---------------------------------------------------------------------------
// Causal flash attention (round-6/8 proven best): swapped-QK^T, in-register
// exp2-space softmax, paired q-tiles (qbA=31-bx heavy, qbB=bx light; B's
// k-range is a subset of A's -> stage nktA tiles, 17 tile-computes/block),
// K/V double-buffered via global_load_lds prefetch, defer-max, XCD swizzle.
// Q [B,H,L,DH], K [B,H,L,DH], Vt [B,H,DH,L]; O -> [B,L,D] bf16.
// ---------------------------------------------------------------------------

#define STAGE(BUF, KT) do {                                                   \
    int ktv = (KT);                                                           \
    _Pragma("unroll")                                                         \
    for (int r = 0; r < 4; r++) {                                             \
        int c = r * 256 + tid;                                                \
        int row = c >> 3, p = c & 7;                                          \
        int fsw = (row & 3) | (((row >> 3) & 1) << 2);                        \
        __builtin_amdgcn_global_load_lds(                                     \
            GPTR(Kp + (size_t)(ktv * 128 + row) * 64 + (p ^ fsw) * 8),        \
            SPTR(Ks[BUF] + (r * 256 + w * 64) * 8), 16, 0, 0);                \
    }                                                                         \
    _Pragma("unroll")                                                         \
    for (int r = 0; r < 4; r++) {                                             \
        int c = r * 256 + tid;                                                \
        int row = c >> 4, p = c & 15;                                         \
        __builtin_amdgcn_global_load_lds(                                     \
            GPTR(Vt + (size_t)row * L_ + ktv * 128 + (p ^ (row & 15)) * 8),   \
            SPTR(Vs[BUF] + (r * 256 + w * 64) * 8), 16, 0, 0);                \
    }                                                                         \
} while (0)

#define ATTN_TILE(BUF, KT, QF, QLANE, MVAR, LVAR, OACC, MASK) do {            \
    f32x4 p8[8] = {};                                                         \
    _Pragma("unroll")                                                         \
    for (int s = 0; s < 2; s++) {                                             \
        bf16x8 kf[8];                                                         \
        _Pragma("unroll")                                                     \
        for (int j = 0; j < 8; j++) {                                         \
            int row = (j >> 1) * 32 + (cl >> 2) * 8 + (j & 1) * 4 + (cl & 3); \
            int fsw = (row & 3) | (((row >> 3) & 1) << 2);                    \
            int ch = s * 4 + g;                                               \
            kf[j] = *(const bf16x8*)(Ks[BUF] + row * 64 + ((ch ^ fsw) * 8));  \
        }                                                                     \
        __builtin_amdgcn_s_setprio(1);                                        \
        _Pragma("unroll")                                                     \
        for (int j = 0; j < 8; j++)                                           \
            p8[j] = __builtin_amdgcn_mfma_f32_16x16x32_bf16(                  \
                kf[j], QF[s], p8[j], 0, 0, 0);                                \
        __builtin_amdgcn_s_setprio(0);                                        \
    }                                                                         \
    float mx0 = -__builtin_inff(), mx1 = -__builtin_inff();                   \
    float mx2 = -__builtin_inff(), mx3 = -__builtin_inff();                   \
    _Pragma("unroll")                                                         \
    for (int j = 0; j < 8; j++) {                                             \
        float v0 = p8[j][0], v1 = p8[j][1], v2 = p8[j][2], v3 = p8[j][3];     \
        if (MASK) {                                                           \
            int ka = (KT) * 128 + (j >> 1) * 32 + g * 8 + ((j & 1) << 2);     \
            v0 = (ka + 0 > (QLANE)) ? -__builtin_inff() : v0;                 \
            v1 = (ka + 1 > (QLANE)) ? -__builtin_inff() : v1;                 \
            v2 = (ka + 2 > (QLANE)) ? -__builtin_inff() : v2;                 \
            v3 = (ka + 3 > (QLANE)) ? -__builtin_inff() : v3;                 \
            p8[j][0] = v0; p8[j][1] = v1; p8[j][2] = v2; p8[j][3] = v3;       \
        }                                                                     \
        mx0 = fmaxf(mx0, v0); mx1 = fmaxf(mx1, v1);                           \
        mx2 = fmaxf(mx2, v2); mx3 = fmaxf(mx3, v3);                           \
    }                                                                         \
    float mx = fmaxf(fmaxf(mx0, mx1), fmaxf(mx2, mx3));                       \
    mx = fmaxf(mx, __shfl_xor(mx, 16));                                       \
    mx = fmaxf(mx, __shfl_xor(mx, 32));                                       \
    if (!__all(mx - MVAR <= 8.f)) {      /* defer-max */                      \
        float mnew = fmaxf(MVAR, mx);                                         \
        float alpha = __builtin_amdgcn_exp2f(MVAR - mnew);                    \
        MVAR = mnew;                                                          \
        LVAR *= alpha;                                                        \
        _Pragma("unroll")                                                     \
        for (int r = 0; r < 4; r++) {                                         \
            float ar = __shfl(alpha, g * 4 + r);                              \
            _Pragma("unroll")                                                 \
            for (int dj = 0; dj < 4; dj++) OACC[dj][r] *= ar;                 \
        }                                                                     \
    }                                                                         \
    float s0 = 0.f, s1 = 0.f, s2 = 0.f, s3 = 0.f;                             \
    _Pragma("unroll")                                                         \
    for (int j = 0; j < 8; j++) {                                             \
        float e0 = __builtin_amdgcn_exp2f(p8[j][0] - MVAR);                   \
        float e1 = __builtin_amdgcn_exp2f(p8[j][1] - MVAR);                   \
        float e2 = __builtin_amdgcn_exp2f(p8[j][2] - MVAR);                   \
        float e3 = __builtin_amdgcn_exp2f(p8[j][3] - MVAR);                   \
        p8[j][0] = e0; p8[j][1] = e1; p8[j][2] = e2; p8[j][3] = e3;           \
        s0 += e0; s1 += e1; s2 += e2; s3 += e3;                               \
    }                                                                         \
    float ls = (s0 + s1) + (s2 + s3);                                         \
    ls += __shfl_xor(ls, 16);                                                 \
    ls += __shfl_xor(ls, 32);                                                 \
    LVAR += ls;                                                               \
    _Pragma("unroll")                                                         \
    for (int ks = 0; ks < 4; ks++) {                                          \
        bf16x8 pf;                                                            \
        _Pragma("unroll")                                                     \
        for (int e = 0; e < 8; e++)                                           \
            pf[e] = (__bf16)p8[2 * ks + (e >> 2)][e & 3];                     \
        bf16x8 vf[4];                                                         \
        _Pragma("unroll")                                                     \
        for (int dj = 0; dj < 4; dj++) {                                      \
            int vrow = dj * 16 + cl;                                          \
            int ch = ks * 4 + g;                                              \
            vf[dj] = *(const bf16x8*)(Vs[BUF] + vrow * 128 + ((ch ^ (vrow & 15)) * 8)); \
        }                                                                     \
        __builtin_amdgcn_s_setprio(1);                                        \
        _Pragma("unroll")                                                     \
        for (int dj = 0; dj < 4; dj++)                                        \
            OACC[dj] = __builtin_amdgcn_mfma_f32_16x16x32_bf16(               \
                pf, vf[dj], OACC[dj], 0, 0, 0);                               \
        __builtin_amdgcn_s_setprio(0);                                        \
    }                                                                         \
} while (0)

__global__ __launch_bounds__(256, 2) void attn_fwd(
        const bhalf* __restrict__ Qb, const bhalf* __restrict__ Kb,
        const bhalf* __restrict__ Vtb, bhalf* __restrict__ Ob) {
    __shared__ bhalf Ks[2][128 * 64];   // [buf][krow][d]  swz (row&3)|(((row>>3)&1)<<2)
    __shared__ bhalf Vs[2][64 * 128];   // [buf][d][kcol]  swz row&15

    // XCD-aware swizzle: same-(b,h) blocks land on one XCD (bid%8 = XCD)
    const int bid  = blockIdx.x;              // 0..511
    const int xcd  = bid & 7, slot = bid >> 3;
    const int bx   = slot & 15;               // 0..15
    const int bh   = xcd + 8 * (slot >> 4);   // 0..31
    const int qbA  = 31 - bx;                 // heavy half (nktA = 9..16)
    const int qbB  = bx;                      // light half, kt-range subset of A

    const int tid = threadIdx.x;
    const int w = tid >> 6, lane = tid & 63;
    const int g = lane >> 4, cl = lane & 15;

    const bhalf* Q  = Qb  + (size_t)bh * L_ * DH_;
    const bhalf* Kp = Kb  + (size_t)bh * L_ * DH_;
    const bhalf* Vt = Vtb + (size_t)bh * DH_ * L_;

    const int q0A = qbA * 64 + w * 16, qlA = q0A + cl;
    const int q0B = qbB * 64 + w * 16, qlB = q0B + cl;

    bf16x8 qfA[2], qfB[2];
#pragma unroll
    for (int s = 0; s < 2; s++) {
        qfA[s] = *(const bf16x8*)(Q + (size_t)(q0A + cl) * 64 + s * 32 + g * 8);
        qfB[s] = *(const bf16x8*)(Q + (size_t)(q0B + cl) * 64 + s * 32 + g * 8);
    }

    f32x4 oA[4] = {}, oB[4] = {};
    float mA = -__builtin_inff(), lA = 0.f;
    float mB = -__builtin_inff(), lB = 0.f;

    const int nktA = (qbA >> 1) + 1;          // 9..16
    const int nktB = (qbB >> 1) + 1;          // 1..8   (nktB < nktA always)

    STAGE(0, 0);
    __syncthreads();

    for (int kt = 0; kt < nktA; ++kt) {
        int cur = kt & 1;
        if (kt + 1 < nktA) STAGE(cur ^ 1, kt + 1);   // prefetch next tile
        if (kt < nktB) {
            ATTN_TILE(cur, kt, qfB, qlB, mB, lB, oB, (kt == nktB - 1));
        }
        ATTN_TILE(cur, kt, qfA, qlA, mA, lA, oA, (kt == nktA - 1));
        __syncthreads();   // next buffer staged; current free to overwrite
    }

    // epilogue: divide by denom (+1e-6 per reference), write O [B,L,D]
    const int b = bh >> 4, h = bh & 15;
#pragma unroll
    for (int r = 0; r < 4; r++) {
        float lrA = __shfl(lA, g * 4 + r);
        float lrB = __shfl(lB, g * 4 + r);
        float invA = 1.f / (lrA + 1e-6f);
        float invB = 1.f / (lrB + 1e-6f);
        int qrA = q0A + g * 4 + r, qrB = q0B + g * 4 + r;
#pragma unroll
        for (int dj = 0; dj < 4; dj++) {
            Ob[((size_t)b * L_ + qrA) * D_ + h * 64 + dj * 16 + cl] =
                f2bf(oA[dj][r] * invA);
            Ob[((size_t)b * L_ + qrB) * D_ + h * 64 + dj * 16 + cl] =
                f2bf(oB[dj][r] * invB);
        }
    }
}

// ---------------------------------------------------------------------------
extern "C" void kernel_launch(void* const* d_in, const int* in_sizes, int n_in,
                              void* d_out, int out_size, void* d_ws, size_t ws_size,
                              hipStream_t stream) {
    const float* x     = (const float*)d_in[0];   // [B,L,D]
    const float* Wqkv  = (const float*)d_in[1];   // [D, 3D]
    const float* bqkv  = (const float*)d_in[2];   // [3D]
    const float* Wproj = (const float*)d_in[3];   // [D, D]
    const float* bproj = (const float*)d_in[4];   // [D]

    char* ws = (char*)d_ws;
    const size_t SZ_WQT = (size_t)3 * D_ * D_ * 2;        //  6 MB  Wqkv^T bf16
    const size_t SZ_WPT = (size_t)D_ * D_ * 2;            //  2 MB  Wproj^T bf16
    const size_t SZ_BUF = (size_t)B_ * H_ * L_ * DH_ * 2; //  8 MB each

    bhalf* Wq_t = (bhalf*)(ws);
    bhalf* Wp_t = (bhalf*)(ws + SZ_WQT);
    bhalf* Qbuf = (bhalf*)(ws + SZ_WQT + SZ_WPT);
    bhalf* Kbuf = (bhalf*)(ws + SZ_WQT + SZ_WPT + SZ_BUF);
    bhalf* Vtbf = (bhalf*)(ws + SZ_WQT + SZ_WPT + 2 * SZ_BUF);
    bhalf* Obuf = (bhalf*)(ws + SZ_WQT + SZ_WPT + 3 * SZ_BUF);

    const int M = B_ * L_;   // 4096

    // 1. weight transposes (f32 -> bf16, [K][N] -> [N][K])
    tr_conv<<<dim3(3 * D_ / 32, D_ / 32), dim3(32, 8), 0, stream>>>(
        Wqkv, Wq_t, D_, 3 * D_);
    tr_conv<<<dim3(D_ / 32, D_ / 32), dim3(32, 8), 0, stream>>>(
        Wproj, Wp_t, D_, D_);

    // 2. QKV projection straight from f32 x (no conversion kernel);
    //    scatter Q (pre-scaled), K [B,H,L,DH], Vt [B,H,DH,L]
    gemm_bt<1><<<dim3(3 * D_ / 128, M / 128), 256, 0, stream>>>(
        x, Wq_t, bqkv, nullptr, Qbuf, Kbuf, Vtbf, M, 3 * D_, D_);

    // 3. causal flash attention -> Obuf [B,L,D] bf16
    attn_fwd<<<dim3(512), 256, 0, stream>>>(Qbuf, Kbuf, Vtbf, Obuf);

    // 4. output projection -> d_out (f32)
    gemm_bt<0><<<dim3(D_ / 128, M / 128), 256, 0, stream>>>(
        Obuf, Wp_t, bproj, (float*)d_out, nullptr, nullptr, nullptr, M, D_, D_);
}